// Round 2
// baseline (11.072 us; speedup 1.0000x reference)
//
#include <hip/hip_runtime.h>
#include <stdint.h>

// Problem constants (from reference): tokens [64, 512, 1024] f32, mask [64, 512] i32.
#define BS  64
#define SEQ 512
#define EMB 1024

__device__ __forceinline__ uint32_t rotl32(uint32_t x, uint32_t r) {
    return (x << r) | (x >> (32u - r));
}

// JAX Threefry-2x32 with key (0, 42)  [jax.random.key(42) -> (seed>>32, seed&0xffffffff)].
// Schedule per jax/_src/prng.py threefry2x32:
//   ks = [k0, k1, k0^k1^0x1BD11BDA]; x0+=ks[0], x1+=ks[1];
//   5 blocks of 4 rounds, rotations alternate {13,15,26,6}/{17,29,16,24};
//   after block i: x0 += ks[(i+1)%3], x1 += ks[(i+2)%3] + (i+1)
__device__ __forceinline__ void threefry2x32_key0_42(uint32_t& x0, uint32_t& x1) {
    const uint32_t ks[3] = {0u, 42u, 0u ^ 42u ^ 0x1BD11BDAu};
    const uint32_t rot[2][4] = {{13u, 15u, 26u, 6u}, {17u, 29u, 16u, 24u}};

    x0 += ks[0];
    x1 += ks[1];
#pragma unroll
    for (int i = 0; i < 5; ++i) {
#pragma unroll
        for (int j = 0; j < 4; ++j) {
            x0 += x1;
            x1 = rotl32(x1, rot[i & 1][j]);
            x1 ^= x0;
        }
        x0 += ks[(i + 1) % 3];
        x1 += ks[(i + 2) % 3] + (uint32_t)(i + 1);
    }
}

__global__ void CondensedEmbracementLayer_69423851372962_kernel(
        const float* __restrict__ tokens,   // [BS, SEQ, EMB]
        const int*   __restrict__ mask,     // [BS, SEQ]
        float*       __restrict__ out) {    // [BS, EMB]
    const int b = blockIdx.x;
    const int t = threadIdx.x;

    __shared__ int s_first_zero;
    if (t == 0) s_first_zero = SEQ;
    __syncthreads();

    // count = sum(cumprod(mask_row)) == index of first zero (SEQ if none).
#pragma unroll
    for (int k = 0; k < SEQ / 256; ++k) {
        const int pos = t + k * 256;
        if (mask[b * SEQ + pos] == 0) atomicMin(&s_first_zero, pos);
    }
    __syncthreads();

    const int   count = s_first_zero;
    const float L     = (float)max(count - 1, 1);

#pragma unroll
    for (int k = 0; k < EMB / 256; ++k) {
        const int e = t + k * 256;
        const uint32_t f = (uint32_t)(b * EMB + e);     // flat index into (BS, EMB)

        // jax_threefry_partitionable=True path (modern JAX default):
        // per-element counter: x0 = hi32(f) = 0, x1 = lo32(f) = f;
        // 32-bit result = out0 ^ out1.
        uint32_t x0 = 0u;
        uint32_t x1 = f;
        threefry2x32_key0_42(x0, x1);
        const uint32_t bits = x0 ^ x1;

        // uniform [0,1): bitcast((bits>>9)|0x3f800000) - 1, then max(0, .)
        float u = __uint_as_float((bits >> 9) | 0x3f800000u) - 1.0f;
        u = fmaxf(u, 0.0f);

        int idx = (int)(u * L);          // truncation toward zero, matches astype(int32)
        idx = min(idx, SEQ - 1);

        out[b * EMB + e] =
            tokens[(size_t)b * SEQ * EMB + (size_t)idx * EMB + e];
    }
}

extern "C" void kernel_launch(void* const* d_in, const int* in_sizes, int n_in,
                              void* d_out, int out_size, void* d_ws, size_t ws_size,
                              hipStream_t stream) {
    const float* tokens = (const float*)d_in[0];
    const int*   mask   = (const int*)d_in[1];
    float*       out    = (float*)d_out;

    CondensedEmbracementLayer_69423851372962_kernel<<<BS, 256, 0, stream>>>(tokens, mask, out);
}

// Round 3
// 9.750 us; speedup vs baseline: 1.1356x; 1.1356x over previous
//
#include <hip/hip_runtime.h>
#include <stdint.h>

// Problem constants (from reference): tokens [64, 512, 1024] f32, mask [64, 512] i32.
#define BS  64
#define SEQ 512
#define EMB 1024
#define BLOCKS_PER_B 4   // EMB / 256 threads

__device__ __forceinline__ uint32_t rotl32(uint32_t x, uint32_t r) {
    return (x << r) | (x >> (32u - r));
}

// JAX Threefry-2x32 with key (0, 42); partitionable counter layout:
// bits[f] = o0 ^ o1 where (o0,o1) = threefry((0,42), x0=0, x1=f).
__device__ __forceinline__ uint32_t threefry_bits_key0_42(uint32_t f) {
    const uint32_t ks[3] = {0u, 42u, 0u ^ 42u ^ 0x1BD11BDAu};
    const uint32_t rot[2][4] = {{13u, 15u, 26u, 6u}, {17u, 29u, 16u, 24u}};

    uint32_t x0 = 0u + ks[0];
    uint32_t x1 = f + ks[1];
#pragma unroll
    for (int i = 0; i < 5; ++i) {
#pragma unroll
        for (int j = 0; j < 4; ++j) {
            x0 += x1;
            x1 = rotl32(x1, rot[i & 1][j]);
            x1 ^= x0;
        }
        x0 += ks[(i + 1) % 3];
        x1 += ks[(i + 2) % 3] + (uint32_t)(i + 1);
    }
    return x0 ^ x1;
}

__global__ void __launch_bounds__(256)
CondensedEmbracementLayer_69423851372962_kernel(
        const float* __restrict__ tokens,   // [BS, SEQ, EMB]
        const int*   __restrict__ mask,     // [BS, SEQ]
        float*       __restrict__ out) {    // [BS, EMB]
    const int bi = blockIdx.x;
    const int b  = bi >> 2;           // / BLOCKS_PER_B
    const int q  = bi & 3;            // % BLOCKS_PER_B
    const int t  = threadIdx.x;
    const int e  = q * 256 + t;

    // Issue the mask load FIRST (threads 0..127 cover the 512-int row as int4),
    // so its latency hides under the Threefry ALU work below.
    int4 mv;
    const bool scans = (t < SEQ / 4 / 1);  // t < 128
    if (t < 128) {
        mv = reinterpret_cast<const int4*>(mask + b * SEQ)[t];
    }
    (void)scans;

    // Threefry while the mask load is in flight (pure ALU, ~40 ops).
    const uint32_t f    = (uint32_t)(b * EMB + e);
    const uint32_t bits = threefry_bits_key0_42(f);
    float u = __uint_as_float((bits >> 9) | 0x3f800000u) - 1.0f;
    u = fmaxf(u, 0.0f);

    __shared__ int s_first_zero;
    if (t == 0) s_first_zero = SEQ;
    __syncthreads();

    if (t < 128) {
        const int p = t * 4;
        if      (mv.x == 0) atomicMin(&s_first_zero, p);
        else if (mv.y == 0) atomicMin(&s_first_zero, p + 1);
        else if (mv.z == 0) atomicMin(&s_first_zero, p + 2);
        else if (mv.w == 0) atomicMin(&s_first_zero, p + 3);
    }
    __syncthreads();

    const int   count = s_first_zero;        // == sum(cumprod(mask_row))
    const float L     = (float)max(count - 1, 1);

    int idx = (int)(u * L);                  // trunc toward zero == astype(int32)
    idx = min(idx, SEQ - 1);

    out[(size_t)b * EMB + e] =
        tokens[(size_t)b * SEQ * EMB + (size_t)idx * EMB + e];
}

extern "C" void kernel_launch(void* const* d_in, const int* in_sizes, int n_in,
                              void* d_out, int out_size, void* d_ws, size_t ws_size,
                              hipStream_t stream) {
    const float* tokens = (const float*)d_in[0];
    const int*   mask   = (const int*)d_in[1];
    float*       out    = (float*)d_out;

    CondensedEmbracementLayer_69423851372962_kernel<<<BS * BLOCKS_PER_B, 256, 0, stream>>>(
        tokens, mask, out);
}

// Round 4
// 9.718 us; speedup vs baseline: 1.1393x; 1.0033x over previous
//
#include <hip/hip_runtime.h>
#include <stdint.h>

// Problem constants (from reference): tokens [64, 512, 1024] f32, mask [64, 512] i32.
#define BS  64
#define SEQ 512
#define EMB 1024
#define BLOCKS_PER_B 16   // EMB / 64 lanes

__device__ __forceinline__ uint32_t rotl32(uint32_t x, uint32_t r) {
    return (x << r) | (x >> (32u - r));
}

// JAX Threefry-2x32 with key (0, 42); partitionable counter layout:
// bits[f] = o0 ^ o1 where (o0,o1) = threefry((0,42), x0=0, x1=f).
__device__ __forceinline__ uint32_t threefry_bits_key0_42(uint32_t f) {
    const uint32_t ks[3] = {0u, 42u, 0u ^ 42u ^ 0x1BD11BDAu};
    const uint32_t rot[2][4] = {{13u, 15u, 26u, 6u}, {17u, 29u, 16u, 24u}};

    uint32_t x0 = 0u + ks[0];
    uint32_t x1 = f + ks[1];
#pragma unroll
    for (int i = 0; i < 5; ++i) {
#pragma unroll
        for (int j = 0; j < 4; ++j) {
            x0 += x1;
            x1 = rotl32(x1, rot[i & 1][j]);
            x1 ^= x0;
        }
        x0 += ks[(i + 1) % 3];
        x1 += ks[(i + 2) % 3] + (uint32_t)(i + 1);
    }
    return x0 ^ x1;
}

// One wave (64 threads) per block; 16 blocks per batch row; 1 output/thread.
// No LDS, no barriers: first-zero count via in-register shuffle-min.
__global__ void __launch_bounds__(64)
CondensedEmbracementLayer_69423851372962_kernel(
        const float* __restrict__ tokens,   // [BS, SEQ, EMB]
        const int*   __restrict__ mask,     // [BS, SEQ]
        float*       __restrict__ out) {    // [BS, EMB]
    const int bi   = blockIdx.x;
    const int b    = bi >> 4;          // / BLOCKS_PER_B
    const int q    = bi & 15;          // % BLOCKS_PER_B
    const int lane = threadIdx.x;      // 0..63
    const int e    = q * 64 + lane;

    // Issue mask loads FIRST: each lane covers 8 ints of the 512-int row.
    const int4* mrow = reinterpret_cast<const int4*>(mask + b * SEQ);
    const int4 m0 = mrow[lane * 2];
    const int4 m1 = mrow[lane * 2 + 1];

    // Threefry while the mask loads are in flight (~44 ALU ops).
    const uint32_t f    = (uint32_t)(b * EMB + e);
    const uint32_t bits = threefry_bits_key0_42(f);
    float u = __uint_as_float((bits >> 9) | 0x3f800000u) - 1.0f;
    u = fmaxf(u, 0.0f);

    // Local first-zero position among this lane's 8 values (SEQ if none).
    int local = SEQ;
    const int p = lane * 8;
    if      (m0.x == 0) local = p;
    else if (m0.y == 0) local = p + 1;
    else if (m0.z == 0) local = p + 2;
    else if (m0.w == 0) local = p + 3;
    else if (m1.x == 0) local = p + 4;
    else if (m1.y == 0) local = p + 5;
    else if (m1.z == 0) local = p + 6;
    else if (m1.w == 0) local = p + 7;

    // Wave-wide min (64 lanes, 6 butterfly steps) = index of first zero = count.
#pragma unroll
    for (int o = 32; o > 0; o >>= 1) {
        local = min(local, __shfl_xor(local, o, 64));
    }

    const float L = (float)max(local - 1, 1);

    int idx = (int)(u * L);            // trunc toward zero == astype(int32)
    idx = min(idx, SEQ - 1);

    out[(size_t)b * EMB + e] =
        tokens[(size_t)b * SEQ * EMB + (size_t)idx * EMB + e];
}

extern "C" void kernel_launch(void* const* d_in, const int* in_sizes, int n_in,
                              void* d_out, int out_size, void* d_ws, size_t ws_size,
                              hipStream_t stream) {
    const float* tokens = (const float*)d_in[0];
    const int*   mask   = (const int*)d_in[1];
    float*       out    = (float*)d_out;

    CondensedEmbracementLayer_69423851372962_kernel<<<BS * BLOCKS_PER_B, 64, 0, stream>>>(
        tokens, mask, out);
}